// Round 2
// baseline (344.019 us; speedup 1.0000x reference)
//
#include <hip/hip_runtime.h>
#include <math.h>

#define HW    3136
#define WIMG  56
#define NPIX  25088   // 8 * 3136
#define CIN   128
#define RED   32
#define NGROUP 8
#define GCH   16
#define KKK   49

// ---------------- K1a: conv1 (1x1) + BN(eval) + ReLU -> t (b,32,hw) fp32 ----------------
__global__ __launch_bounds__(256) void k_conv1(const float* __restrict__ x,
    const float* __restrict__ w, const float* __restrict__ bias,
    const float* __restrict__ gam, const float* __restrict__ bet,
    const float* __restrict__ mu, const float* __restrict__ var,
    float* __restrict__ t)
{
    int id = blockIdx.x * 256 + threadIdx.x;
    int o4 = id / NPIX;              // 0..7, wave-uniform (NPIX % 256 == 0)
    int pg = id - o4 * NPIX;
    int b  = pg / HW;
    int p  = pg - b * HW;
    const float* xb = x + (size_t)b * CIN * HW + p;
    int o = o4 * 4;
    const float* w0 = w + (size_t)(o + 0) * CIN;
    const float* w1 = w + (size_t)(o + 1) * CIN;
    const float* w2 = w + (size_t)(o + 2) * CIN;
    const float* w3 = w + (size_t)(o + 3) * CIN;
    float a0 = 0.f, a1 = 0.f, a2 = 0.f, a3 = 0.f;
    #pragma unroll 8
    for (int c = 0; c < CIN; ++c) {
        float xv = xb[(size_t)c * HW];
        a0 += w0[c] * xv;
        a1 += w1[c] * xv;
        a2 += w2[c] * xv;
        a3 += w3[c] * xv;
    }
    float acc[4] = {a0, a1, a2, a3};
    #pragma unroll
    for (int i = 0; i < 4; ++i) {
        int oo = o + i;
        float v  = acc[i] + bias[oo];
        float sc = gam[oo] * rsqrtf(var[oo] + 1e-5f);
        v = (v - mu[oo]) * sc + bet[oo];
        v = fmaxf(v, 0.f);
        t[((size_t)b * RED + oo) * HW + p] = v;
    }
}

// ---------------- K1b: conv2 (1x1) -> wgt (b,392,hw) fp32 ----------------
__global__ __launch_bounds__(256) void k_conv2(const float* __restrict__ t,
    const float* __restrict__ w, const float* __restrict__ bias,
    float* __restrict__ wgt)
{
    int id = blockIdx.x * 256 + threadIdx.x;
    int k  = id / NPIX;              // 0..48, wave-uniform
    int pg = id - k * NPIX;
    int b  = pg / HW;
    int p  = pg - b * HW;
    const float* tb = t + (size_t)b * RED * HW + p;
    float tv[RED];
    #pragma unroll
    for (int j = 0; j < RED; ++j) tv[j] = tb[(size_t)j * HW];
    #pragma unroll
    for (int gg = 0; gg < NGROUP; ++gg) {
        int o = gg * KKK + k;
        const float* wr = w + (size_t)o * RED;
        float acc = bias[o];
        #pragma unroll
        for (int j = 0; j < RED; ++j) acc += wr[j] * tv[j];
        wgt[((size_t)b * 392 + o) * HW + p] = acc;
    }
}

// ---------------- K1c: involution -> inv (b,128,hw) fp32 ----------------
__global__ __launch_bounds__(256) void k_invol(const float* __restrict__ x,
    const float* __restrict__ wgt, float* __restrict__ inv)
{
    int id = blockIdx.x * 256 + threadIdx.x;
    int g  = id / NPIX;              // 0..7, wave-uniform
    int pg = id - g * NPIX;
    int b  = pg / HW;
    int p  = pg - b * HW;
    int py = p / WIMG;
    int px = p - py * WIMG;
    const float* wb = wgt + ((size_t)b * 392 + g * KKK) * HW + p;
    const float* xb = x   + ((size_t)b * CIN + g * GCH) * HW;
    float acc[GCH];
    #pragma unroll
    for (int cc = 0; cc < GCH; ++cc) acc[cc] = 0.f;
    for (int k = 0; k < KKK; ++k) {
        int ky = k / 7;
        int dy = ky - 3;
        int dx = (k - ky * 7) - 3;
        int yy = py + dy, xx = px + dx;
        if (yy < 0 || yy >= WIMG || xx < 0 || xx >= WIMG) continue;
        float wv = wb[(size_t)k * HW];
        int off  = yy * WIMG + xx;
        #pragma unroll
        for (int cc = 0; cc < GCH; ++cc)
            acc[cc] += wv * xb[(size_t)cc * HW + off];
    }
    float* ob = inv + ((size_t)b * CIN + g * GCH) * HW + p;
    #pragma unroll
    for (int cc = 0; cc < GCH; ++cc) ob[(size_t)cc * HW] = acc[cc];
}

// ---------------- K2: LayerNorm (over channels) -> y (npix,128) fp32 channels-last ----------------
__global__ __launch_bounds__(64) void k_ln(const float* __restrict__ inv,
    const float* __restrict__ lnw, const float* __restrict__ lnb,
    float* __restrict__ y)
{
    int id = blockIdx.x * 64 + threadIdx.x;   // global pixel 0..25087
    int b  = id / HW;
    int p  = id - b * HW;
    const float* ib = inv + (size_t)b * CIN * HW + p;
    float s = 0.f, s2 = 0.f;
    #pragma unroll 8
    for (int c = 0; c < CIN; ++c) {
        float v = ib[(size_t)c * HW];
        s += v; s2 += v * v;
    }
    float m    = s  * (1.0f / CIN);
    float vr   = s2 * (1.0f / CIN) - m * m;
    float rstd = rsqrtf(vr + 1e-6f);
    float* yb = y + (size_t)id * CIN;
    #pragma unroll 4
    for (int c4 = 0; c4 < CIN / 4; ++c4) {
        float v[4];
        #pragma unroll
        for (int i = 0; i < 4; ++i) {
            int c = c4 * 4 + i;
            v[i] = (ib[(size_t)c * HW] - m) * rstd * lnw[c] + lnb[c];
        }
        *(float4*)(yb + c4 * 4) = make_float4(v[0], v[1], v[2], v[3]);
    }
}

// ---------------- GEMM: C[M x N] = A[M x KD] * B[N x KD]^T (+epilogue) ----------------
// EPI 0: +bias, exact GELU, store fp32 to Cf (row stride 512)
// EPI 1: +bias, +residual x (fp32, channels-first), store fp32 channels-first to Cb
template<int KD, int EPI>
__global__ __launch_bounds__(256) void k_gemm(const float* __restrict__ A,
    const float* __restrict__ B, const float* __restrict__ bias,
    const float* __restrict__ xres, float* __restrict__ Cf, float* __restrict__ Cb)
{
    __shared__ float sa[32 * 68];   // [k][row], stride 68 keeps 16B alignment, 2-way max conflict
    __shared__ float sb[32 * 68];
    int tid = threadIdx.x;
    int tx = tid & 15, ty = tid >> 4;       // 16 x 16 thread grid
    int p0 = blockIdx.x * 64, j0 = blockIdx.y * 64;
    int kk = tid & 31, rr = tid >> 5;       // staging coords
    float acc[4][4] = {{0.f}};
    for (int kc = 0; kc < KD; kc += 32) {
        __syncthreads();
        #pragma unroll
        for (int pass = 0; pass < 8; ++pass) {
            int r = pass * 8 + rr;
            sa[kk * 68 + r] = A[(size_t)(p0 + r) * KD + kc + kk];
            sb[kk * 68 + r] = B[(size_t)(j0 + r) * KD + kc + kk];
        }
        __syncthreads();
        #pragma unroll
        for (int k = 0; k < 32; ++k) {
            float4 av = *(const float4*)&sa[k * 68 + tx * 4];
            float4 bv = *(const float4*)&sb[k * 68 + ty * 4];
            acc[0][0] += av.x * bv.x; acc[0][1] += av.x * bv.y; acc[0][2] += av.x * bv.z; acc[0][3] += av.x * bv.w;
            acc[1][0] += av.y * bv.x; acc[1][1] += av.y * bv.y; acc[1][2] += av.y * bv.z; acc[1][3] += av.y * bv.w;
            acc[2][0] += av.z * bv.x; acc[2][1] += av.z * bv.y; acc[2][2] += av.z * bv.z; acc[2][3] += av.z * bv.w;
            acc[3][0] += av.w * bv.x; acc[3][1] += av.w * bv.y; acc[3][2] += av.w * bv.z; acc[3][3] += av.w * bv.w;
        }
    }
    if (EPI == 0) {
        #pragma unroll
        for (int ii = 0; ii < 4; ++ii) {
            int p = p0 + tx * 4 + ii;
            float v[4];
            #pragma unroll
            for (int jj = 0; jj < 4; ++jj) {
                float h = acc[ii][jj] + bias[j0 + ty * 4 + jj];
                v[jj] = 0.5f * h * (1.f + erff(h * 0.70710678118654752f));
            }
            *(float4*)&Cf[(size_t)p * 512 + j0 + ty * 4] = make_float4(v[0], v[1], v[2], v[3]);
        }
    } else {
        int b   = p0 / HW;                  // 64-pixel tile never straddles an image (3136 % 64 == 0)
        int pin = (p0 - b * HW) + tx * 4;
        #pragma unroll
        for (int jj = 0; jj < 4; ++jj) {
            int c = j0 + ty * 4 + jj;
            size_t base = ((size_t)b * CIN + c) * HW + pin;
            float bj = bias[c];
            float4 rv = *(const float4*)&xres[base];
            float4 ov = make_float4(acc[0][jj] + bj + rv.x,
                                    acc[1][jj] + bj + rv.y,
                                    acc[2][jj] + bj + rv.z,
                                    acc[3][jj] + bj + rv.w);
            *(float4*)&Cb[base] = ov;
        }
    }
}

extern "C" void kernel_launch(void* const* d_in, const int* in_sizes, int n_in,
                              void* d_out, int out_size, void* d_ws, size_t ws_size,
                              hipStream_t stream) {
    const float* x       = (const float*)d_in[0];
    const float* conv1_w = (const float*)d_in[1];
    const float* conv1_b = (const float*)d_in[2];
    const float* bn_g    = (const float*)d_in[3];
    const float* bn_b    = (const float*)d_in[4];
    const float* bn_m    = (const float*)d_in[5];
    const float* bn_v    = (const float*)d_in[6];
    const float* conv2_w = (const float*)d_in[7];
    const float* conv2_b = (const float*)d_in[8];
    const float* ln_w    = (const float*)d_in[9];
    const float* ln_b    = (const float*)d_in[10];
    const float* w1      = (const float*)d_in[11];
    const float* b1      = (const float*)d_in[12];
    const float* w2      = (const float*)d_in[13];
    const float* b2      = (const float*)d_in[14];
    float* out = (float*)d_out;

    float* ws  = (float*)d_ws;
    float* t    = ws;                        //   802,816 f
    float* wgt  = t   + 802816;              // 9,834,496 f
    float* inv  = wgt + 9834496;             // 3,211,264 f
    float* y    = inv + 3211264;             // 3,211,264 f
    float* hid  = y   + 3211264;             // 12,845,056 f   (total ~119.6 MB)

    k_conv1<<<784, 256, 0, stream>>>(x, conv1_w, conv1_b, bn_g, bn_b, bn_m, bn_v, t);
    k_conv2<<<4802, 256, 0, stream>>>(t, conv2_w, conv2_b, wgt);
    k_invol<<<784, 256, 0, stream>>>(x, wgt, inv);
    k_ln<<<392, 64, 0, stream>>>(inv, ln_w, ln_b, y);
    k_gemm<128, 0><<<dim3(392, 8), 256, 0, stream>>>(y, w1, b1, nullptr, hid, nullptr);
    k_gemm<512, 1><<<dim3(392, 2), 256, 0, stream>>>(hid, w2, b2, x, nullptr, out);
}

// Round 3
// 223.745 us; speedup vs baseline: 1.5376x; 1.5376x over previous
//
#include <hip/hip_runtime.h>
#include <hip/hip_bf16.h>
#include <math.h>

#define HW    3136
#define WIMG  56
#define NPIX  25088   // 8 * 3136
#define CIN   128
#define RED   32
#define NGROUP 8
#define GCH   16
#define KKK   49

typedef __attribute__((ext_vector_type(8))) short short8;
typedef __attribute__((ext_vector_type(4))) float f32x4;
typedef unsigned short ushort_t;

static __device__ __forceinline__ ushort_t f2b(float f) {
    union { __hip_bfloat16 b; unsigned short u; } cv;
    cv.b = __float2bfloat16(f);
    return cv.u;
}

// ---------------- weight fp32 -> bf16 conversion (w1: 65536, w2: 65536) ----------------
__global__ __launch_bounds__(256) void k_wcvt(const float* __restrict__ w1,
    const float* __restrict__ w2, ushort_t* __restrict__ w1b, ushort_t* __restrict__ w2b)
{
    int i = blockIdx.x * 256 + threadIdx.x;
    if (i < 65536) w1b[i] = f2b(w1[i]);
    else           w2b[i - 65536] = f2b(w2[i - 65536]);
}

// ---------------- K1a: conv1 (1x1) + BN(eval) + ReLU -> t (b,32,hw) fp32 ----------------
__global__ __launch_bounds__(256) void k_conv1(const float* __restrict__ x,
    const float* __restrict__ w, const float* __restrict__ bias,
    const float* __restrict__ gam, const float* __restrict__ bet,
    const float* __restrict__ mu, const float* __restrict__ var,
    float* __restrict__ t)
{
    int o4 = (blockIdx.x * 256) / NPIX;         // block-uniform
    int pg = blockIdx.x * 256 + threadIdx.x - o4 * NPIX;
    int b  = pg / HW;
    int p  = pg - b * HW;
    const float* xb = x + (size_t)b * CIN * HW + p;
    int o = o4 * 4;
    const float* w0 = w + (size_t)(o + 0) * CIN;
    const float* w1 = w + (size_t)(o + 1) * CIN;
    const float* w2 = w + (size_t)(o + 2) * CIN;
    const float* w3 = w + (size_t)(o + 3) * CIN;
    float a0 = 0.f, a1 = 0.f, a2 = 0.f, a3 = 0.f;
    #pragma unroll 8
    for (int c = 0; c < CIN; ++c) {
        float xv = xb[(size_t)c * HW];
        a0 += w0[c] * xv;
        a1 += w1[c] * xv;
        a2 += w2[c] * xv;
        a3 += w3[c] * xv;
    }
    float acc[4] = {a0, a1, a2, a3};
    #pragma unroll
    for (int i = 0; i < 4; ++i) {
        int oo = o + i;
        float v  = acc[i] + bias[oo];
        float sc = gam[oo] * rsqrtf(var[oo] + 1e-5f);
        v = (v - mu[oo]) * sc + bet[oo];
        v = fmaxf(v, 0.f);
        t[((size_t)b * RED + oo) * HW + p] = v;
    }
}

// ---------------- fused conv2 + involution -> inv (b,128,hw) fp32 ----------------
__global__ __launch_bounds__(256) void k_inv_f(const float* __restrict__ x,
    const float* __restrict__ t, const float* __restrict__ w2,
    const float* __restrict__ cb, float* __restrict__ inv)
{
    int g  = (blockIdx.x * 256) / NPIX;          // block-uniform group
    int pg = blockIdx.x * 256 + threadIdx.x - g * NPIX;
    int b  = pg / HW;
    int p  = pg - b * HW;
    int py = p / WIMG;
    int px = p - py * WIMG;
    // load the 32 reduced features at this pixel
    const float* tb = t + (size_t)b * RED * HW + p;
    float tv[RED];
    #pragma unroll
    for (int j = 0; j < RED; ++j) tv[j] = tb[(size_t)j * HW];
    const float* xb = x + ((size_t)b * CIN + g * GCH) * HW;
    float acc[GCH];
    #pragma unroll
    for (int cc = 0; cc < GCH; ++cc) acc[cc] = 0.f;
    const float* w2g = w2 + (size_t)g * KKK * RED;   // block-uniform base
    const float* cbg = cb + g * KKK;
    for (int k = 0; k < KKK; ++k) {
        int ky = k / 7;
        int dy = ky - 3;
        int dx = (k - ky * 7) - 3;
        int yy = py + dy, xx = px + dx;
        // dynamic kernel weight: conv2 row dot t  (w2 row is block-uniform -> scalar loads)
        const float* wr = w2g + k * RED;
        float wk = cbg[k];
        #pragma unroll
        for (int j = 0; j < RED; ++j) wk += wr[j] * tv[j];
        if (yy < 0 || yy >= WIMG || xx < 0 || xx >= WIMG) continue;
        int off = yy * WIMG + xx;
        #pragma unroll
        for (int cc = 0; cc < GCH; ++cc)
            acc[cc] += wk * xb[(size_t)cc * HW + off];
    }
    float* ob = inv + ((size_t)b * CIN + g * GCH) * HW + p;
    #pragma unroll
    for (int cc = 0; cc < GCH; ++cc) ob[(size_t)cc * HW] = acc[cc];
}

// ---------------- K2: LayerNorm -> y (npix,128) bf16 channels-last ----------------
__global__ __launch_bounds__(256) void k_ln(const float* __restrict__ inv,
    const float* __restrict__ lnw, const float* __restrict__ lnb,
    ushort_t* __restrict__ yb)
{
    int id = blockIdx.x * 256 + threadIdx.x;   // global pixel
    int b  = id / HW;
    int p  = id - b * HW;
    const float* ib = inv + (size_t)b * CIN * HW + p;
    float s = 0.f, s2 = 0.f;
    #pragma unroll 8
    for (int c = 0; c < CIN; ++c) {
        float v = ib[(size_t)c * HW];
        s += v; s2 += v * v;
    }
    float m    = s  * (1.0f / CIN);
    float vr   = s2 * (1.0f / CIN) - m * m;
    float rstd = rsqrtf(vr + 1e-6f);
    ushort_t* yr = yb + (size_t)id * CIN;
    #pragma unroll
    for (int c8 = 0; c8 < CIN / 8; ++c8) {
        unsigned int pk[4];
        #pragma unroll
        for (int h = 0; h < 4; ++h) {
            int c = c8 * 8 + h * 2;
            float v0 = (ib[(size_t)c * HW] - m) * rstd * lnw[c] + lnb[c];
            float v1 = (ib[(size_t)(c + 1) * HW] - m) * rstd * lnw[c + 1] + lnb[c + 1];
            pk[h] = (unsigned int)f2b(v0) | ((unsigned int)f2b(v1) << 16);
        }
        *(uint4*)&yr[c8 * 8] = make_uint4(pk[0], pk[1], pk[2], pk[3]);
    }
}

// ---------------- MFMA GEMM: C[M x N] = A[M x KD] (bf16) * B[N x KD]^T (bf16) ----------------
// BN = 128, waves 2x2. BM in {64,128}. TM = BM/32, TN = 4.
// EPI 0: +bias(fp32), exact GELU, store bf16 row-major (stride 512) to Cb
// EPI 1: +bias(fp32), +residual x (fp32 channels-first), store fp32 channels-first to Cf
template<int KD, int BM, int TM, int EPI>
__global__ __launch_bounds__(256) void k_gemm(const ushort_t* __restrict__ A,
    const ushort_t* __restrict__ B, const float* __restrict__ bias,
    const float* __restrict__ xres, ushort_t* __restrict__ Cb, float* __restrict__ Cf)
{
    constexpr int TN = 4;
    constexpr int APASS = BM / 64;
    __shared__ short sA[BM * 40];      // [row][40], 16B-aligned rows, <=2-way bank alias
    __shared__ short sB[128 * 40];
    int tid  = threadIdx.x;
    int lane = tid & 63;
    int wv   = tid >> 6;
    int wm   = wv & 1, wn = wv >> 1;
    int ln15 = lane & 15, quad = lane >> 4;
    int lr = tid >> 2, lc = tid & 3;          // staging: row / 16B-chunk
    int p0 = blockIdx.x * BM, j0 = blockIdx.y * 128;

    f32x4 acc[TM][TN];
    #pragma unroll
    for (int i = 0; i < TM; ++i)
        #pragma unroll
        for (int j = 0; j < TN; ++j) acc[i][j] = (f32x4)0.f;

    uint4 ga[APASS], gb[2];
    #pragma unroll
    for (int a = 0; a < APASS; ++a)
        ga[a] = *(const uint4*)&A[(size_t)(p0 + a * 64 + lr) * KD + lc * 8];
    #pragma unroll
    for (int bpass = 0; bpass < 2; ++bpass)
        gb[bpass] = *(const uint4*)&B[(size_t)(j0 + bpass * 64 + lr) * KD + lc * 8];

    for (int kc = 0; kc < KD; kc += 32) {
        __syncthreads();
        #pragma unroll
        for (int a = 0; a < APASS; ++a)
            *(uint4*)&sA[(a * 64 + lr) * 40 + lc * 8] = ga[a];
        #pragma unroll
        for (int bpass = 0; bpass < 2; ++bpass)
            *(uint4*)&sB[(bpass * 64 + lr) * 40 + lc * 8] = gb[bpass];
        __syncthreads();
        if (kc + 32 < KD) {
            #pragma unroll
            for (int a = 0; a < APASS; ++a)
                ga[a] = *(const uint4*)&A[(size_t)(p0 + a * 64 + lr) * KD + kc + 32 + lc * 8];
            #pragma unroll
            for (int bpass = 0; bpass < 2; ++bpass)
                gb[bpass] = *(const uint4*)&B[(size_t)(j0 + bpass * 64 + lr) * KD + kc + 32 + lc * 8];
        }
        short8 af[TM], bf[TN];
        #pragma unroll
        for (int tm = 0; tm < TM; ++tm)
            af[tm] = *(const short8*)&sA[(wm * (BM / 2) + tm * 16 + ln15) * 40 + quad * 8];
        #pragma unroll
        for (int tn = 0; tn < TN; ++tn)
            bf[tn] = *(const short8*)&sB[(wn * 64 + tn * 16 + ln15) * 40 + quad * 8];
        #pragma unroll
        for (int tm = 0; tm < TM; ++tm)
            #pragma unroll
            for (int tn = 0; tn < TN; ++tn)
                acc[tm][tn] = __builtin_amdgcn_mfma_f32_16x16x32_bf16(af[tm], bf[tn], acc[tm][tn], 0, 0, 0);
    }

    if (EPI == 0) {
        #pragma unroll
        for (int tm = 0; tm < TM; ++tm) {
            int mbase = p0 + wm * (BM / 2) + tm * 16 + quad * 4;
            #pragma unroll
            for (int tn = 0; tn < TN; ++tn) {
                int n = j0 + wn * 64 + tn * 16 + ln15;
                float bj = bias[n];
                #pragma unroll
                for (int r = 0; r < 4; ++r) {
                    float h = acc[tm][tn][r] + bj;
                    float gv = 0.5f * h * (1.f + erff(h * 0.70710678118654752f));
                    Cb[(size_t)(mbase + r) * 512 + n] = f2b(gv);
                }
            }
        }
    } else {
        #pragma unroll
        for (int tm = 0; tm < TM; ++tm) {
            int mg = p0 + wm * (BM / 2) + tm * 16 + quad * 4;  // global pixel, %4==0
            int b  = mg / HW;
            int p  = mg - b * HW;
            #pragma unroll
            for (int tn = 0; tn < TN; ++tn) {
                int c = j0 + wn * 64 + tn * 16 + ln15;
                size_t base = ((size_t)b * CIN + c) * HW + p;
                float bj = bias[c];
                float4 rv = *(const float4*)&xres[base];
                float4 ov = make_float4(acc[tm][tn][0] + bj + rv.x,
                                        acc[tm][tn][1] + bj + rv.y,
                                        acc[tm][tn][2] + bj + rv.z,
                                        acc[tm][tn][3] + bj + rv.w);
                *(float4*)&Cf[base] = ov;
            }
        }
    }
}

extern "C" void kernel_launch(void* const* d_in, const int* in_sizes, int n_in,
                              void* d_out, int out_size, void* d_ws, size_t ws_size,
                              hipStream_t stream) {
    const float* x       = (const float*)d_in[0];
    const float* conv1_w = (const float*)d_in[1];
    const float* conv1_b = (const float*)d_in[2];
    const float* bn_g    = (const float*)d_in[3];
    const float* bn_b    = (const float*)d_in[4];
    const float* bn_m    = (const float*)d_in[5];
    const float* bn_v    = (const float*)d_in[6];
    const float* conv2_w = (const float*)d_in[7];
    const float* conv2_b = (const float*)d_in[8];
    const float* ln_w    = (const float*)d_in[9];
    const float* ln_b    = (const float*)d_in[10];
    const float* w1      = (const float*)d_in[11];
    const float* b1      = (const float*)d_in[12];
    const float* w2      = (const float*)d_in[13];
    const float* b2      = (const float*)d_in[14];
    float* out = (float*)d_out;

    float* ws   = (float*)d_ws;
    float* t    = ws;                                  // 802,816 f   (3.2 MB)
    float* inv  = t + 802816;                          // 3,211,264 f (12.8 MB)
    ushort_t* yb  = (ushort_t*)(inv + 3211264);        // 3,211,264 us (6.4 MB)
    ushort_t* hb  = yb + (size_t)NPIX * 512 / 4 * 1;   // placeholder, fixed below
    hb = yb + (size_t)NPIX * CIN;                      // 12,845,056 us (25.7 MB)
    ushort_t* w1b = hb + (size_t)NPIX * 512;           // 65,536 us
    ushort_t* w2b = w1b + 65536;                       // 65,536 us

    k_wcvt <<<512, 256, 0, stream>>>(w1, w2, w1b, w2b);
    k_conv1<<<784, 256, 0, stream>>>(x, conv1_w, conv1_b, bn_g, bn_b, bn_m, bn_v, t);
    k_inv_f<<<784, 256, 0, stream>>>(x, t, conv2_w, conv2_b, inv);
    k_ln   <<<98, 256, 0, stream>>>(inv, ln_w, ln_b, yb);
    k_gemm<128, 128, 4, 0><<<dim3(196, 4), 256, 0, stream>>>(yb, w1b, b1, nullptr, hb, nullptr);
    k_gemm<512, 64, 2, 1><<<dim3(392, 1), 256, 0, stream>>>(hb, w2b, b2, x, nullptr, out);
}